// Round 8
// baseline (1021.319 us; speedup 1.0000x reference)
//
#include <hip/hip_runtime.h>
#include <math.h>

#define NSC 64
#define NVC 64
#define EMB 32
#define NTYPES 20
#define NB 8
#define RH 16
#define LAYERS 2
#define CUTV 3.5f
#define HSTEP 0.1f

// ---------------------------------------------------------------------------
// Exact LAPACK-style Householder QR of Ku^T (64x2) -> Q (64x2), wave-parallel.
// ---------------------------------------------------------------------------
__device__ __forceinline__ float wave_sum(float t)
{
  #pragma unroll
  for (int mm = 1; mm < 64; mm <<= 1) t += __shfl_xor(t, mm, 64);
  return t;
}

__global__ void qr_kernel(const float* __restrict__ Ku, float* __restrict__ Q)
{
  const int i = threadIdx.x;  // 64 lanes
  float a0 = Ku[i], a1 = Ku[64 + i];
  const float xn2 = wave_sum((i >= 1) ? a0 * a0 : 0.f);
  const float alpha = __shfl(a0, 0, 64);
  const float beta0 = -copysignf(sqrtf(alpha * alpha + xn2), alpha);
  const float tau0 = (beta0 - alpha) / beta0;
  const float inv0 = 1.f / (alpha - beta0);
  const float v0 = (i == 0) ? 1.f : a0 * inv0;
  const float w = wave_sum(v0 * a1);
  a1 -= tau0 * w * v0;
  const float alpha1 = __shfl(a1, 1, 64);
  const float xn2b = wave_sum((i >= 2) ? a1 * a1 : 0.f);
  const float beta1 = -copysignf(sqrtf(alpha1 * alpha1 + xn2b), alpha1);
  const float tau1 = (beta1 - alpha1) / beta1;
  const float inv1 = 1.f / (alpha1 - beta1);
  const float v1 = (i == 0) ? 0.f : ((i == 1) ? 1.f : a1 * inv1);
  const float t1v = ((i == 1) ? 1.f : 0.f) - tau1 * v1;
  const float d = wave_sum(v0 * t1v);
  Q[i * 2 + 0] = ((i == 0) ? 1.f : 0.f) - tau0 * v0;
  Q[i * 2 + 1] = t1v - tau0 * d * v0;
}

// ---------------------------------------------------------------------------
// State layout: st[node][p][lane], p in {0:s, 1:vx, 2:vy, 3:vz}; 256 floats/node.
// ---------------------------------------------------------------------------
__global__ void init_state(const float* __restrict__ x, const float* __restrict__ Qm,
                           float* __restrict__ st0, int* __restrict__ cnt, int n)
{
  const int i = blockIdx.x * 256 + threadIdx.x;
  const int node = i >> 6, lane = i & 63;
  if (node < n) {
    const float q0 = Qm[lane * 2 + 0], q1 = Qm[lane * 2 + 1];
    const float* xp = x + (size_t)node * 6;
    float* sp = st0 + (size_t)node * 256 + lane;
    sp[0]   = 0.f;
    sp[64]  = xp[0] * q0 + xp[3] * q1;
    sp[128] = xp[1] * q0 + xp[4] * q1;
    sp[192] = xp[2] * q0 + xp[5] * q1;
  }
  if (i < n) cnt[i] = 0;
}

__global__ void hist_kernel(const int* __restrict__ edst, int* __restrict__ cnt, int m)
{
  const int e = blockIdx.x * 256 + threadIdx.x;
  if (e < m) atomicAdd(&cnt[edst[e]], 1);
}

// Single-block exclusive scan of counts.
__global__ void scan_kernel(int* cnt, int* off, int n)
{
  __shared__ int lds[1024];
  const int t = threadIdx.x;
  const int CH = (n + 1023) >> 10;
  const int base = t * CH;
  int local[16];
  int run = 0;
  for (int j = 0; j < CH; ++j) {
    int v = (base + j < n) ? cnt[base + j] : 0;
    local[j] = run;
    run += v;
  }
  lds[t] = run;
  __syncthreads();
  for (int s = 1; s < 1024; s <<= 1) {
    int v = (t >= s) ? lds[t - s] : 0;
    __syncthreads();
    lds[t] += v;
    __syncthreads();
  }
  const int excl = lds[t] - run;
  for (int j = 0; j < CH; ++j) {
    if (base + j < n) {
      int o = excl + local[j];
      off[base + j] = o;
      cnt[base + j] = o;
    }
  }
  if (t == 1023) off[n] = lds[1023];
}

__global__ void scatter_kernel(const int* __restrict__ edst, int* __restrict__ cursor,
                               int* __restrict__ csr, int m)
{
  const int e = blockIdx.x * 256 + threadIdx.x;
  if (e < m) {
    int p = atomicAdd(&cursor[edst[e]], 1);
    csr[p] = e;
  }
}

// Edge arrays in CSR (destination-sorted) order — computed once.
__global__ void reorder_kernel(const int* __restrict__ csr,
                               const int* __restrict__ esrc, const int* __restrict__ edst,
                               int* __restrict__ esrc_s, int* __restrict__ edst_s, int m)
{
  const int k = blockIdx.x * 256 + threadIdx.x;
  if (k < m) {
    const int e = csr[k];
    esrc_s[k] = esrc[e];
    edst_s[k] = edst[e];
  }
}

// ---------------------------------------------------------------------------
// Per-(layer,type) folded self-connection weights, output-parallel.
// ---------------------------------------------------------------------------
__global__ void type_weights(const float* __restrict__ embed,
                             const float* __restrict__ Wss,
                             const float* __restrict__ Wsv,
                             float* __restrict__ Ws, float* __restrict__ Wv,
                             int total_s, int total_v)
{
  const int i = blockIdx.x * 256 + threadIdx.x;
  if (i < total_s) {
    const int bid = i >> 13;
    const int p = i & 8191;
    const int l = bid / NTYPES, t = bid % NTYPES;
    const int s = p >> 7, o = p & 127;
    const float* ar = embed + t * EMB;
    const float* wp = Wss + ((size_t)(l * 64 + s) * EMB) * 128 + o;
    float acc = 0.f;
    #pragma unroll
    for (int e = 0; e < EMB; ++e) acc = fmaf(ar[e], wp[e * 128], acc);
    Ws[i] = acc;
  } else {
    const int j = i - total_s;
    if (j < total_v) {
      const int bid = j >> 12;
      const int p = j & 4095;
      const int l = bid / NTYPES, t = bid % NTYPES;
      const int v = p >> 6, u = p & 63;
      const float* ar = embed + t * EMB;
      const float* wp = Wsv + ((size_t)(l * 64 + v) * EMB) * 64 + u;
      float acc = 0.f;
      #pragma unroll
      for (int e = 0; e < EMB; ++e) acc = fmaf(ar[e], wp[e * 64], acc);
      Wv[j] = acc;
    }
  }
}

// ---------------------------------------------------------------------------
// Per-edge geometry + first MLP layer, in CSR order.
// ea4[k] = (eaX, eaY, eaZ, 0);  hidb[k][16] = f32 hidden activations.
// ---------------------------------------------------------------------------
__global__ void edge_geom(const float* __restrict__ xv,
                          const int* __restrict__ esrc_s, const int* __restrict__ edst_s,
                          const float* __restrict__ Wr1l, const float* __restrict__ br1l,
                          float4* __restrict__ ea4, float* __restrict__ hidb, int m)
{
  const int k = blockIdx.x * 256 + threadIdx.x;
  if (k >= m) return;
  const int s = esrc_s[k], d = edst_s[k];
  const float ex = xv[(size_t)s * 6 + 0] - xv[(size_t)d * 6 + 0];
  const float ey = xv[(size_t)s * 6 + 1] - xv[(size_t)d * 6 + 1];
  const float ez = xv[(size_t)s * 6 + 2] - xv[(size_t)d * 6 + 2];
  const float len = sqrtf(ex * ex + ey * ey + ez * ez);
  const float invl = 1.f / len;
  const float u = len * (1.f / CUTV);
  const float arg = (float)M_PI * u;
  float sa, ca;
  __sincosf(arg, &sa, &ca);
  const float vv = 2.f * (u - 1.f);
  float cut = 0.5f * (1.f - (2.f * ca * ca - 1.f));
  cut = (vv > 0.f) ? 0.f : cut;
  cut = (vv < -1.f) ? 1.f : cut;
  const float cc = cut * 1.7320508075688772f * invl;
  ea4[k] = make_float4(cc * ex, cc * ey, cc * ez, 0.f);
  float bess[NB];
  const float amp = 2.1380899352993948f * invl;  // sqrt(2/CUT)*sqrt(NB)
  const float twoc = 2.f * ca;
  float sm1 = 0.f, scur = sa;
  #pragma unroll
  for (int kk = 0; kk < NB; ++kk) {
    bess[kk] = amp * scur;
    const float snext = twoc * scur - sm1;
    sm1 = scur; scur = snext;
  }
  float hid[RH];
  #pragma unroll
  for (int j = 0; j < RH; ++j) {
    float h = br1l[j];
    #pragma unroll
    for (int kk = 0; kk < NB; ++kk) h = fmaf(bess[kk], Wr1l[kk * RH + j], h);
    hid[j] = h / (1.f + expf(-h));   // silu
  }
  float4* hp = (float4*)(hidb + (size_t)k * 16);
  hp[0] = make_float4(hid[0],  hid[1],  hid[2],  hid[3]);
  hp[1] = make_float4(hid[4],  hid[5],  hid[6],  hid[7]);
  hp[2] = make_float4(hid[8],  hid[9],  hid[10], hid[11]);
  hp[3] = make_float4(hid[12], hid[13], hid[14], hid[15]);
}

// ---------------------------------------------------------------------------
// One wave (block=64) per destination node. Per 32-edge batch:
//  MLP phase: lane = edge; channel loop is wave-uniform so Wr2/br2 loads are
//  SCALAR (SGPR operands, zero VGPR cost); w stored to XOR-swizzled f32 LDS.
//  Consumption: lane = channel; 1-edge-ahead st/ea prefetch pipeline.
// All arithmetic f32.
// ---------------------------------------------------------------------------
__global__ __launch_bounds__(64) void gather_update(
    const int* __restrict__ off, const int* __restrict__ esrc_s,
    const float4* __restrict__ ea4, const float* __restrict__ hidb,
    const float* __restrict__ st_in, const int* __restrict__ nattr,
    const float* __restrict__ Ws, const float* __restrict__ Wv,
    const float* __restrict__ Wr2l, const float* __restrict__ br2l,
    const float* __restrict__ Qm,
    float* __restrict__ st_out, float* __restrict__ xv_out, int n)
{
  __shared__ float wl[8192];   // 32 KB: [256 ch][32 e], e XOR-swizzled by ch&31
  const int lane = threadIdx.x;
  const int node = blockIdx.x;
  if (node >= n) return;
  const int el = lane & 31;   // edge slot in MLP phase (upper half duplicates)
  const int sw = lane & 31;   // read swizzle

  float aS1 = 0.f, aS2 = 0.f, aV0 = 0.f, aV1 = 0.f, aV2 = 0.f;
  const int k0 = off[node], k1 = off[node + 1];
  if (k0 < k1) {
    // prime the st/ea pipeline with edge k0
    int srcN = esrc_s[k0];
    const float* pp = st_in + (size_t)srcN * 256 + lane;
    float ssN = pp[0], vxN = pp[64], vyN = pp[128], vzN = pp[192];
    float4 eaN = ea4[k0];
    srcN = (k0 + 1 < k1) ? esrc_s[k0 + 1] : srcN;

    for (int kb = k0; kb < k1; kb += 32) {
      // ---- MLP phase: w[ch][e] for up to 32 edges ----
      int ke = kb + el; if (ke > k1 - 1) ke = k1 - 1;
      const float4* hp = (const float4*)(hidb + (size_t)ke * 16);
      const float4 h0 = hp[0], h1 = hp[1], h2 = hp[2], h3 = hp[3];
      const float hid[RH] = { h0.x,h0.y,h0.z,h0.w, h1.x,h1.y,h1.z,h1.w,
                              h2.x,h2.y,h2.z,h2.w, h3.x,h3.y,h3.z,h3.w };
      for (int ch = 0; ch < 256; ch += 4) {
        float a0 = br2l[ch + 0];
        float a1 = br2l[ch + 1];
        float a2 = br2l[ch + 2];
        float a3 = br2l[ch + 3];
        #pragma unroll
        for (int j = 0; j < RH; ++j) {
          const float* wr = Wr2l + j * 256 + ch;   // wave-uniform -> s_load
          a0 = fmaf(wr[0], hid[j], a0);
          a1 = fmaf(wr[1], hid[j], a1);
          a2 = fmaf(wr[2], hid[j], a2);
          a3 = fmaf(wr[3], hid[j], a3);
        }
        // upper-half lanes write identical data to identical addresses (free)
        wl[(ch + 0) * 32 + (el ^ ((ch + 0) & 31))] = a0;
        wl[(ch + 1) * 32 + (el ^ ((ch + 1) & 31))] = a1;
        wl[(ch + 2) * 32 + (el ^ ((ch + 2) & 31))] = a2;
        wl[(ch + 3) * 32 + (el ^ ((ch + 3) & 31))] = a3;
      }
      // ---- consumption: lane = channel ----
      const int kend = (kb + 32 < k1) ? kb + 32 : k1;
      for (int k = kb; k < kend; ++k) {
        const float ss = ssN, vx = vxN, vy = vyN, vz = vzN;
        const float4 ea = eaN;
        // prefetch next edge's st/ea (src known since last iteration)
        const float* pN = st_in + (size_t)srcN * 256 + lane;
        ssN = pN[0]; vxN = pN[64]; vyN = pN[128]; vzN = pN[192];
        const int kn = (k + 1 < k1) ? k + 1 : k;
        eaN = ea4[kn];
        srcN = (k + 2 < k1) ? esrc_s[k + 2] : srcN;
        // w from LDS (f32, bias already folded)
        const int ee = (k - kb) ^ sw;
        const float wAv = wl[lane * 32 + ee];
        const float wBv = wl[2048 + lane * 32 + ee];
        const float wCv = wl[4096 + lane * 32 + ee];
        const float wDv = wl[6144 + lane * 32 + ee];
        const float dt = vx * ea.x + vy * ea.y + vz * ea.z;
        aS1 = fmaf(wBv, dt, aS1);
        aS2 = fmaf(wDv, dt, aS2);
        const float t = wAv * ss;
        aV0 += t * ea.x + wCv * (vy * ea.z - vz * ea.y);
        aV1 += t * ea.y + wCv * (vz * ea.x - vx * ea.z);
        aV2 += t * ea.z + wCv * (vx * ea.y - vy * ea.x);
      }
    }
  }
  const float inv_deg = 0.17677669529663687f;  // 1/sqrt(32)

  // node phase: sc_s / sc_v matvecs with per-type folded weights
  const int ty = nattr[node];
  const float* WsT = Ws + (size_t)ty * 8192;
  const float* WvT = Wv + (size_t)ty * 4096;
  const float* own = st_in + (size_t)node * 256 + lane;
  const float ys_own = own[0], v0x = own[64], v0y = own[128], v0z = own[192];
  float oS1 = 0.f, oS2 = 0.f, oV0 = 0.f, oV1 = 0.f, oV2 = 0.f;
  #pragma unroll 4
  for (int s2 = 0; s2 < 64; ++s2) {
    const float yss = __shfl(ys_own, s2, 64);
    const float b0 = __shfl(v0x, s2, 64);
    const float b1 = __shfl(v0y, s2, 64);
    const float b2 = __shfl(v0z, s2, 64);
    const float wsA = WsT[s2 * 128 + lane];
    const float wsB = WsT[s2 * 128 + 64 + lane];
    const float wvv = WvT[s2 * 64 + lane];
    oS1 = fmaf(yss, wsA, oS1);
    oS2 = fmaf(yss, wsB, oS2);
    oV0 = fmaf(b0, wvv, oV0);
    oV1 = fmaf(b1, wvv, oV1);
    oV2 = fmaf(b2, wvv, oV2);
  }
  const float outS1 = oS1 + aS1 * inv_deg;
  const float outS2 = oS2 + aS2 * inv_deg;
  const float sig1 = 1.f / (1.f + expf(-outS1));
  const float gate = 1.f / (1.f + expf(-outS2));
  const float ysn = ys_own + HSTEP * outS1 * sig1;
  const float gf = HSTEP * gate;
  const float yvn0 = v0x + gf * (oV0 + aV0 * inv_deg);
  const float yvn1 = v0y + gf * (oV1 + aV1 * inv_deg);
  const float yvn2 = v0z + gf * (oV2 + aV2 * inv_deg);
  float* op = st_out + (size_t)node * 256 + lane;
  op[0] = ysn; op[64] = yvn0; op[128] = yvn1; op[192] = yvn2;

  // x_v[n,c,d] = sum_h yvn[h,d] * Q[h,c]  -> butterfly reduce 6 scalars
  const float q0 = Qm[lane * 2 + 0], q1 = Qm[lane * 2 + 1];
  float pr[6] = { yvn0 * q0, yvn1 * q0, yvn2 * q0,
                  yvn0 * q1, yvn1 * q1, yvn2 * q1 };
  #pragma unroll
  for (int mm = 1; mm < 64; mm <<= 1) {
    #pragma unroll
    for (int i = 0; i < 6; ++i) pr[i] += __shfl_xor(pr[i], mm, 64);
  }
  if (lane == 0) {
    #pragma unroll
    for (int i = 0; i < 6; ++i) xv_out[(size_t)node * 6 + i] = pr[i];
  }
}

// ---------------------------------------------------------------------------
extern "C" void kernel_launch(void* const* d_in, const int* in_sizes, int n_in,
                              void* d_out, int out_size, void* d_ws, size_t ws_size,
                              hipStream_t stream)
{
  const float* x     = (const float*)d_in[0];
  const int*   nattr = (const int*)d_in[2];
  const int*   esrc  = (const int*)d_in[3];
  const int*   edst  = (const int*)d_in[4];
  const float* embed = (const float*)d_in[5];
  const float* Ku    = (const float*)d_in[6];
  const float* Wss   = (const float*)d_in[7];
  const float* Wsv   = (const float*)d_in[8];
  const float* Wr1   = (const float*)d_in[9];
  const float* br1   = (const float*)d_in[10];
  const float* Wr2   = (const float*)d_in[11];
  const float* br2   = (const float*)d_in[12];
  const int n = in_sizes[0] / 6;
  const int m = in_sizes[3];

  char* p = (char*)d_ws;
  auto alloc = [&](size_t bytes) -> char* {
    char* r = p;
    p += (bytes + 255) & ~(size_t)255;
    return r;
  };
  int*   off    = (int*)alloc((size_t)(n + 1) * 4);
  int*   cursor = (int*)alloc((size_t)n * 4);
  int*   csr    = (int*)alloc((size_t)m * 4);
  int*   esrc_s = (int*)alloc((size_t)m * 4);
  int*   edst_s = (int*)alloc((size_t)m * 4);
  float* Q      = (float*)alloc(128 * 4);
  float* Ws     = (float*)alloc((size_t)LAYERS * NTYPES * 64 * 128 * 4);
  float* Wv     = (float*)alloc((size_t)LAYERS * NTYPES * 64 * 64 * 4);
  float* st0    = (float*)alloc((size_t)n * 256 * 4);
  float* st1    = (float*)alloc((size_t)n * 256 * 4);
  float* xvb    = (float*)alloc((size_t)n * 6 * 4);
  float4* ea4   = (float4*)alloc((size_t)m * 16);
  float* hidb   = (float*)alloc((size_t)m * 16 * 4);

  const int total_s = LAYERS * NTYPES * 64 * 128;
  const int total_v = LAYERS * NTYPES * 64 * 64;

  qr_kernel<<<1, 64, 0, stream>>>(Ku, Q);
  init_state<<<(n * 64 + 255) / 256, 256, 0, stream>>>(x, Q, st0, cursor, n);
  hist_kernel<<<(m + 255) / 256, 256, 0, stream>>>(edst, cursor, m);
  scan_kernel<<<1, 1024, 0, stream>>>(cursor, off, n);
  scatter_kernel<<<(m + 255) / 256, 256, 0, stream>>>(edst, cursor, csr, m);
  reorder_kernel<<<(m + 255) / 256, 256, 0, stream>>>(csr, esrc, edst, esrc_s, edst_s, m);
  type_weights<<<(total_s + total_v + 255) / 256, 256, 0, stream>>>(
      embed, Wss, Wsv, Ws, Wv, total_s, total_v);

  const float* xv_cur = x;
  const float* st_cur = st0;
  float* st_nxt = st1;
  for (int l = 0; l < LAYERS; ++l) {
    edge_geom<<<(m + 255) / 256, 256, 0, stream>>>(
        xv_cur, esrc_s, edst_s, Wr1 + l * NB * RH, br1 + l * RH, ea4, hidb, m);
    float* xv_out = (l == LAYERS - 1) ? (float*)d_out : xvb;
    gather_update<<<n, 64, 0, stream>>>(
        off, esrc_s, ea4, hidb, st_cur, nattr,
        Ws + (size_t)l * NTYPES * 8192, Wv + (size_t)l * NTYPES * 4096,
        Wr2 + l * RH * 256, br2 + l * 256, Q,
        st_nxt, xv_out, n);
    xv_cur = xv_out;
    float* ts = (float*)st_cur; st_cur = st_nxt; st_nxt = ts;
  }
}

// Round 10
// 321.609 us; speedup vs baseline: 3.1756x; 3.1756x over previous
//
#include <hip/hip_runtime.h>
#include <math.h>

#define NSC 64
#define NVC 64
#define EMB 32
#define NTYPES 20
#define NB 8
#define RH 16
#define LAYERS 2
#define CUTV 3.5f
#define HSTEP 0.1f

// ---------------------------------------------------------------------------
// Exact LAPACK-style Householder QR of Ku^T (64x2) -> Q (64x2), wave-parallel.
// ---------------------------------------------------------------------------
__device__ __forceinline__ float wave_sum(float t)
{
  #pragma unroll
  for (int mm = 1; mm < 64; mm <<= 1) t += __shfl_xor(t, mm, 64);
  return t;
}

__global__ void qr_kernel(const float* __restrict__ Ku, float* __restrict__ Q)
{
  const int i = threadIdx.x;  // 64 lanes
  float a0 = Ku[i], a1 = Ku[64 + i];
  const float xn2 = wave_sum((i >= 1) ? a0 * a0 : 0.f);
  const float alpha = __shfl(a0, 0, 64);
  const float beta0 = -copysignf(sqrtf(alpha * alpha + xn2), alpha);
  const float tau0 = (beta0 - alpha) / beta0;
  const float inv0 = 1.f / (alpha - beta0);
  const float v0 = (i == 0) ? 1.f : a0 * inv0;
  const float w = wave_sum(v0 * a1);
  a1 -= tau0 * w * v0;
  const float alpha1 = __shfl(a1, 1, 64);
  const float xn2b = wave_sum((i >= 2) ? a1 * a1 : 0.f);
  const float beta1 = -copysignf(sqrtf(alpha1 * alpha1 + xn2b), alpha1);
  const float tau1 = (beta1 - alpha1) / beta1;
  const float inv1 = 1.f / (alpha1 - beta1);
  const float v1 = (i == 0) ? 0.f : ((i == 1) ? 1.f : a1 * inv1);
  const float t1v = ((i == 1) ? 1.f : 0.f) - tau1 * v1;
  const float d = wave_sum(v0 * t1v);
  Q[i * 2 + 0] = ((i == 0) ? 1.f : 0.f) - tau0 * v0;
  Q[i * 2 + 1] = t1v - tau0 * d * v0;
}

// ---------------------------------------------------------------------------
// State layout: st4[node*64+lane] = (s, vx, vy, vz) — one float4 per (node,ch).
// ---------------------------------------------------------------------------
__global__ void init_state(const float* __restrict__ x, const float* __restrict__ Qm,
                           float4* __restrict__ st0, int* __restrict__ cnt, int n)
{
  const int i = blockIdx.x * 256 + threadIdx.x;
  const int node = i >> 6, lane = i & 63;
  if (node < n) {
    const float q0 = Qm[lane * 2 + 0], q1 = Qm[lane * 2 + 1];
    const float* xp = x + (size_t)node * 6;
    st0[i] = make_float4(0.f,
                         xp[0] * q0 + xp[3] * q1,
                         xp[1] * q0 + xp[4] * q1,
                         xp[2] * q0 + xp[5] * q1);
  }
  if (i < n) cnt[i] = 0;
}

__global__ void hist_kernel(const int* __restrict__ edst, int* __restrict__ cnt, int m)
{
  const int e = blockIdx.x * 256 + threadIdx.x;
  if (e < m) atomicAdd(&cnt[edst[e]], 1);
}

// Single-block exclusive scan of counts.
__global__ void scan_kernel(int* cnt, int* off, int n)
{
  __shared__ int lds[1024];
  const int t = threadIdx.x;
  const int CH = (n + 1023) >> 10;
  const int base = t * CH;
  int local[16];
  int run = 0;
  for (int j = 0; j < CH; ++j) {
    int v = (base + j < n) ? cnt[base + j] : 0;
    local[j] = run;
    run += v;
  }
  lds[t] = run;
  __syncthreads();
  for (int s = 1; s < 1024; s <<= 1) {
    int v = (t >= s) ? lds[t - s] : 0;
    __syncthreads();
    lds[t] += v;
    __syncthreads();
  }
  const int excl = lds[t] - run;
  for (int j = 0; j < CH; ++j) {
    if (base + j < n) {
      int o = excl + local[j];
      off[base + j] = o;
      cnt[base + j] = o;
    }
  }
  if (t == 1023) off[n] = lds[1023];
}

__global__ void scatter_kernel(const int* __restrict__ edst, int* __restrict__ cursor,
                               int* __restrict__ csr, int m)
{
  const int e = blockIdx.x * 256 + threadIdx.x;
  if (e < m) {
    int p = atomicAdd(&cursor[edst[e]], 1);
    csr[p] = e;
  }
}

// Edge arrays in CSR (destination-sorted) order — computed once.
__global__ void reorder_kernel(const int* __restrict__ csr,
                               const int* __restrict__ esrc, const int* __restrict__ edst,
                               int* __restrict__ esrc_s, int* __restrict__ edst_s, int m)
{
  const int k = blockIdx.x * 256 + threadIdx.x;
  if (k < m) {
    const int e = csr[k];
    esrc_s[k] = esrc[e];
    edst_s[k] = edst[e];
  }
}

// ---------------------------------------------------------------------------
// Per-(layer,type) folded self-connection weights, output-parallel.
// ---------------------------------------------------------------------------
__global__ void type_weights(const float* __restrict__ embed,
                             const float* __restrict__ Wss,
                             const float* __restrict__ Wsv,
                             float* __restrict__ Ws, float* __restrict__ Wv,
                             int total_s, int total_v)
{
  const int i = blockIdx.x * 256 + threadIdx.x;
  if (i < total_s) {
    const int bid = i >> 13;
    const int p = i & 8191;
    const int l = bid / NTYPES, t = bid % NTYPES;
    const int s = p >> 7, o = p & 127;
    const float* ar = embed + t * EMB;
    const float* wp = Wss + ((size_t)(l * 64 + s) * EMB) * 128 + o;
    float acc = 0.f;
    #pragma unroll
    for (int e = 0; e < EMB; ++e) acc = fmaf(ar[e], wp[e * 128], acc);
    Ws[i] = acc;
  } else {
    const int j = i - total_s;
    if (j < total_v) {
      const int bid = j >> 12;
      const int p = j & 4095;
      const int l = bid / NTYPES, t = bid % NTYPES;
      const int v = p >> 6, u = p & 63;
      const float* ar = embed + t * EMB;
      const float* wp = Wsv + ((size_t)(l * 64 + v) * EMB) * 64 + u;
      float acc = 0.f;
      #pragma unroll
      for (int e = 0; e < EMB; ++e) acc = fmaf(ar[e], wp[e * 64], acc);
      Wv[j] = acc;
    }
  }
}

// Wt[l][ch][j] = Wr2[l][j][ch] — transposed so a channel's 16 coeffs are
// contiguous (4x global_load_dwordx4 per channel group).
__global__ void transpose_wr2(const float* __restrict__ Wr2, float* __restrict__ Wt)
{
  const int t = blockIdx.x * 256 + threadIdx.x;
  if (t >= LAYERS * 256) return;
  const int l = t >> 8, ch = t & 255;
  #pragma unroll
  for (int j = 0; j < RH; ++j)
    Wt[(size_t)l * 4096 + ch * RH + j] = Wr2[(size_t)l * 4096 + j * 256 + ch];
}

// ---------------------------------------------------------------------------
// Per-edge geometry + first MLP layer, in CSR order.
// ea4[k] = (eaX, eaY, eaZ, 0);  hidb[k][16] = f32 hidden activations.
// ---------------------------------------------------------------------------
__global__ void edge_geom(const float* __restrict__ xv,
                          const int* __restrict__ esrc_s, const int* __restrict__ edst_s,
                          const float* __restrict__ Wr1l, const float* __restrict__ br1l,
                          float4* __restrict__ ea4, float* __restrict__ hidb, int m)
{
  const int k = blockIdx.x * 256 + threadIdx.x;
  if (k >= m) return;
  const int s = esrc_s[k], d = edst_s[k];
  const float ex = xv[(size_t)s * 6 + 0] - xv[(size_t)d * 6 + 0];
  const float ey = xv[(size_t)s * 6 + 1] - xv[(size_t)d * 6 + 1];
  const float ez = xv[(size_t)s * 6 + 2] - xv[(size_t)d * 6 + 2];
  const float len = sqrtf(ex * ex + ey * ey + ez * ez);
  const float invl = 1.f / len;
  const float u = len * (1.f / CUTV);
  const float arg = (float)M_PI * u;
  float sa, ca;
  __sincosf(arg, &sa, &ca);
  const float vv = 2.f * (u - 1.f);
  float cut = 0.5f * (1.f - (2.f * ca * ca - 1.f));
  cut = (vv > 0.f) ? 0.f : cut;
  cut = (vv < -1.f) ? 1.f : cut;
  const float cc = cut * 1.7320508075688772f * invl;
  ea4[k] = make_float4(cc * ex, cc * ey, cc * ez, 0.f);
  float bess[NB];
  const float amp = 2.1380899352993948f * invl;  // sqrt(2/CUT)*sqrt(NB)
  const float twoc = 2.f * ca;
  float sm1 = 0.f, scur = sa;
  #pragma unroll
  for (int kk = 0; kk < NB; ++kk) {
    bess[kk] = amp * scur;
    const float snext = twoc * scur - sm1;
    sm1 = scur; scur = snext;
  }
  float hid[RH];
  #pragma unroll
  for (int j = 0; j < RH; ++j) {
    float h = br1l[j];
    #pragma unroll
    for (int kk = 0; kk < NB; ++kk) h = fmaf(bess[kk], Wr1l[kk * RH + j], h);
    hid[j] = h / (1.f + expf(-h));   // silu
  }
  float4* hp = (float4*)(hidb + (size_t)k * 16);
  hp[0] = make_float4(hid[0],  hid[1],  hid[2],  hid[3]);
  hp[1] = make_float4(hid[4],  hid[5],  hid[6],  hid[7]);
  hp[2] = make_float4(hid[8],  hid[9],  hid[10], hid[11]);
  hp[3] = make_float4(hid[12], hid[13], hid[14], hid[15]);
}

// ---------------------------------------------------------------------------
// One wave per destination node (4 waves / 256-thread block, zero LDS).
// The 64 Wr2 coefficients for this lane's 4 channels are loaded via inline-asm
// global_load_dwordx4 — asm-defined values cannot be rematerialized or
// re-loaded by the compiler, so they stay resident in VGPRs across the edge
// loop (rounds 4/5 failed because normal loads were re-issued per iteration).
// ---------------------------------------------------------------------------
#define PIN_LOAD4(dst, addr)                                                  \
  asm volatile("global_load_dwordx4 %0, %1, off" : "=v"(dst) : "v"(addr) : "memory")

#define MLP16(res, W0, W1, W2, W3)                                            \
  res = fmaf(g1.x, W0.x, res); res = fmaf(g1.y, W0.y, res);                   \
  res = fmaf(g1.z, W0.z, res); res = fmaf(g1.w, W0.w, res);                   \
  res = fmaf(g2.x, W1.x, res); res = fmaf(g2.y, W1.y, res);                   \
  res = fmaf(g2.z, W1.z, res); res = fmaf(g2.w, W1.w, res);                   \
  res = fmaf(g3.x, W2.x, res); res = fmaf(g3.y, W2.y, res);                   \
  res = fmaf(g3.z, W2.z, res); res = fmaf(g3.w, W2.w, res);                   \
  res = fmaf(g4.x, W3.x, res); res = fmaf(g4.y, W3.y, res);                   \
  res = fmaf(g4.z, W3.z, res); res = fmaf(g4.w, W3.w, res);

__global__ __launch_bounds__(256, 2) void gather_update(
    const int* __restrict__ off, const int* __restrict__ esrc_s,
    const float4* __restrict__ ea4, const float* __restrict__ hidb,
    const float4* __restrict__ st_in, const int* __restrict__ nattr,
    const float* __restrict__ Ws, const float* __restrict__ Wv,
    const float* __restrict__ Wtl, const float* __restrict__ br2l,
    const float* __restrict__ Qm,
    float4* __restrict__ st_out, float* __restrict__ xv_out, int n)
{
  const int lane = threadIdx.x & 63;
  const int node = blockIdx.x * 4 + (threadIdx.x >> 6);
  if (node >= n) return;

  // --- pin this lane's 64 Wr2 coefficients in VGPRs (opaque asm loads) ---
  float4 WA0, WA1, WA2, WA3, WB0, WB1, WB2, WB3;
  float4 WC0, WC1, WC2, WC3, WD0, WD1, WD2, WD3;
  {
    const float* pa = Wtl + (size_t)lane * RH;
    const float* pb = Wtl + (size_t)(64 + lane) * RH;
    const float* pc = Wtl + (size_t)(128 + lane) * RH;
    const float* pd = Wtl + (size_t)(192 + lane) * RH;
    PIN_LOAD4(WA0, pa);  PIN_LOAD4(WA1, pa + 4);  PIN_LOAD4(WA2, pa + 8);  PIN_LOAD4(WA3, pa + 12);
    PIN_LOAD4(WB0, pb);  PIN_LOAD4(WB1, pb + 4);  PIN_LOAD4(WB2, pb + 8);  PIN_LOAD4(WB3, pb + 12);
    PIN_LOAD4(WC0, pc);  PIN_LOAD4(WC1, pc + 4);  PIN_LOAD4(WC2, pc + 8);  PIN_LOAD4(WC3, pc + 12);
    PIN_LOAD4(WD0, pd);  PIN_LOAD4(WD1, pd + 4);  PIN_LOAD4(WD2, pd + 8);  PIN_LOAD4(WD3, pd + 12);
    asm volatile("s_waitcnt vmcnt(0)" ::: "memory");
    __builtin_amdgcn_sched_barrier(0);
  }
  const float bA = br2l[lane], bB = br2l[64 + lane],
              bC = br2l[128 + lane], bD = br2l[192 + lane];

  float aS1 = 0.f, aS2 = 0.f, aV0 = 0.f, aV1 = 0.f, aV2 = 0.f;
  const int k0 = off[node], k1 = off[node + 1];
  if (k0 < k1) {
    // software pipeline: st + geometry for edge k prefetched at iteration k-1
    int srcN = esrc_s[k0];
    float4 stN = st_in[(size_t)srcN * 64 + lane];
    float4 eaN = ea4[k0];
    const float4* hN = (const float4*)(hidb + (size_t)k0 * 16);
    float4 g1N = hN[0], g2N = hN[1], g3N = hN[2], g4N = hN[3];
    srcN = (k0 + 1 < k1) ? esrc_s[k0 + 1] : srcN;

    for (int k = k0; k < k1; ++k) {
      const float4 stc = stN, ea = eaN;
      const float4 g1 = g1N, g2 = g2N, g3 = g3N, g4 = g4N;
      // issue next edge's loads before current compute
      stN = st_in[(size_t)srcN * 64 + lane];
      const int kn = (k + 1 < k1) ? (k + 1) : k;
      eaN = ea4[kn];
      const float4* hp = (const float4*)(hidb + (size_t)kn * 16);
      g1N = hp[0]; g2N = hp[1]; g3N = hp[2]; g4N = hp[3];
      srcN = (k + 2 < k1) ? esrc_s[k + 2] : srcN;
      // radial MLP second layer: 64 FMAs on pinned coefficients
      float wA = bA, wB = bB, wC = bC, wD = bD;
      MLP16(wA, WA0, WA1, WA2, WA3)
      MLP16(wB, WB0, WB1, WB2, WB3)
      MLP16(wC, WC0, WC1, WC2, WC3)
      MLP16(wD, WD0, WD1, WD2, WD3)
      const float ss = stc.x, vx = stc.y, vy = stc.z, vz = stc.w;
      const float dt = vx * ea.x + vy * ea.y + vz * ea.z;
      aS1 = fmaf(wB, dt, aS1);
      aS2 = fmaf(wD, dt, aS2);
      const float t = wA * ss;
      aV0 += t * ea.x + wC * (vy * ea.z - vz * ea.y);
      aV1 += t * ea.y + wC * (vz * ea.x - vx * ea.z);
      aV2 += t * ea.z + wC * (vx * ea.y - vy * ea.x);
    }
  }
  const float inv_deg = 0.17677669529663687f;  // 1/sqrt(32)

  // node phase: sc_s / sc_v matvecs with per-type folded weights
  const int ty = nattr[node];
  const float* WsT = Ws + (size_t)ty * 8192;
  const float* WvT = Wv + (size_t)ty * 4096;
  const float4 own = st_in[(size_t)node * 64 + lane];
  const float ys_own = own.x, v0x = own.y, v0y = own.z, v0z = own.w;
  float oS1 = 0.f, oS2 = 0.f, oV0 = 0.f, oV1 = 0.f, oV2 = 0.f;
  #pragma unroll 4
  for (int s2 = 0; s2 < 64; ++s2) {
    const float yss = __shfl(ys_own, s2, 64);
    const float b0 = __shfl(v0x, s2, 64);
    const float b1 = __shfl(v0y, s2, 64);
    const float b2 = __shfl(v0z, s2, 64);
    const float wsA = WsT[s2 * 128 + lane];
    const float wsB = WsT[s2 * 128 + 64 + lane];
    const float wvv = WvT[s2 * 64 + lane];
    oS1 = fmaf(yss, wsA, oS1);
    oS2 = fmaf(yss, wsB, oS2);
    oV0 = fmaf(b0, wvv, oV0);
    oV1 = fmaf(b1, wvv, oV1);
    oV2 = fmaf(b2, wvv, oV2);
  }
  const float outS1 = oS1 + aS1 * inv_deg;
  const float outS2 = oS2 + aS2 * inv_deg;
  const float sig1 = 1.f / (1.f + expf(-outS1));
  const float gate = 1.f / (1.f + expf(-outS2));
  const float ysn = ys_own + HSTEP * outS1 * sig1;
  const float gf = HSTEP * gate;
  const float yvn0 = v0x + gf * (oV0 + aV0 * inv_deg);
  const float yvn1 = v0y + gf * (oV1 + aV1 * inv_deg);
  const float yvn2 = v0z + gf * (oV2 + aV2 * inv_deg);
  st_out[(size_t)node * 64 + lane] = make_float4(ysn, yvn0, yvn1, yvn2);

  // x_v[n,c,d] = sum_h yvn[h,d] * Q[h,c]  -> butterfly reduce 6 scalars
  const float q0 = Qm[lane * 2 + 0], q1 = Qm[lane * 2 + 1];
  float pr[6] = { yvn0 * q0, yvn1 * q0, yvn2 * q0,
                  yvn0 * q1, yvn1 * q1, yvn2 * q1 };
  #pragma unroll
  for (int mm = 1; mm < 64; mm <<= 1) {
    #pragma unroll
    for (int i = 0; i < 6; ++i) pr[i] += __shfl_xor(pr[i], mm, 64);
  }
  if (lane == 0) {
    #pragma unroll
    for (int i = 0; i < 6; ++i) xv_out[(size_t)node * 6 + i] = pr[i];
  }
}

// ---------------------------------------------------------------------------
extern "C" void kernel_launch(void* const* d_in, const int* in_sizes, int n_in,
                              void* d_out, int out_size, void* d_ws, size_t ws_size,
                              hipStream_t stream)
{
  const float* x     = (const float*)d_in[0];
  const int*   nattr = (const int*)d_in[2];
  const int*   esrc  = (const int*)d_in[3];
  const int*   edst  = (const int*)d_in[4];
  const float* embed = (const float*)d_in[5];
  const float* Ku    = (const float*)d_in[6];
  const float* Wss   = (const float*)d_in[7];
  const float* Wsv   = (const float*)d_in[8];
  const float* Wr1   = (const float*)d_in[9];
  const float* br1   = (const float*)d_in[10];
  const float* Wr2   = (const float*)d_in[11];
  const float* br2   = (const float*)d_in[12];
  const int n = in_sizes[0] / 6;
  const int m = in_sizes[3];

  char* p = (char*)d_ws;
  auto alloc = [&](size_t bytes) -> char* {
    char* r = p;
    p += (bytes + 255) & ~(size_t)255;
    return r;
  };
  int*    off    = (int*)alloc((size_t)(n + 1) * 4);
  int*    cursor = (int*)alloc((size_t)n * 4);
  int*    csr    = (int*)alloc((size_t)m * 4);
  int*    esrc_s = (int*)alloc((size_t)m * 4);
  int*    edst_s = (int*)alloc((size_t)m * 4);
  float*  Q      = (float*)alloc(128 * 4);
  float*  Ws     = (float*)alloc((size_t)LAYERS * NTYPES * 64 * 128 * 4);
  float*  Wv     = (float*)alloc((size_t)LAYERS * NTYPES * 64 * 64 * 4);
  float4* st0    = (float4*)alloc((size_t)n * 64 * 16);
  float4* st1    = (float4*)alloc((size_t)n * 64 * 16);
  float*  xvb    = (float*)alloc((size_t)n * 6 * 4);
  float4* ea4    = (float4*)alloc((size_t)m * 16);
  float*  hidb   = (float*)alloc((size_t)m * 16 * 4);
  float*  Wt     = (float*)alloc((size_t)LAYERS * 4096 * 4);

  const int total_s = LAYERS * NTYPES * 64 * 128;
  const int total_v = LAYERS * NTYPES * 64 * 64;

  qr_kernel<<<1, 64, 0, stream>>>(Ku, Q);
  init_state<<<(n * 64 + 255) / 256, 256, 0, stream>>>(x, Q, st0, cursor, n);
  hist_kernel<<<(m + 255) / 256, 256, 0, stream>>>(edst, cursor, m);
  scan_kernel<<<1, 1024, 0, stream>>>(cursor, off, n);
  scatter_kernel<<<(m + 255) / 256, 256, 0, stream>>>(edst, cursor, csr, m);
  reorder_kernel<<<(m + 255) / 256, 256, 0, stream>>>(csr, esrc, edst, esrc_s, edst_s, m);
  type_weights<<<(total_s + total_v + 255) / 256, 256, 0, stream>>>(
      embed, Wss, Wsv, Ws, Wv, total_s, total_v);
  transpose_wr2<<<2, 256, 0, stream>>>(Wr2, Wt);

  const float* xv_cur = x;
  const float4* st_cur = st0;
  float4* st_nxt = st1;
  for (int l = 0; l < LAYERS; ++l) {
    edge_geom<<<(m + 255) / 256, 256, 0, stream>>>(
        xv_cur, esrc_s, edst_s, Wr1 + l * NB * RH, br1 + l * RH, ea4, hidb, m);
    float* xv_out = (l == LAYERS - 1) ? (float*)d_out : xvb;
    gather_update<<<(n + 3) / 4, 256, 0, stream>>>(
        off, esrc_s, ea4, hidb, st_cur, nattr,
        Ws + (size_t)l * NTYPES * 8192, Wv + (size_t)l * NTYPES * 4096,
        Wt + (size_t)l * 4096, br2 + l * 256, Q,
        st_nxt, xv_out, n);
    xv_cur = xv_out;
    float4* ts = (float4*)st_cur; st_cur = st_nxt; st_nxt = ts;
  }
}